// Round 6
// baseline (450.484 us; speedup 1.0000x reference)
//
#include <hip/hip_runtime.h>
#include <math.h>

// Problem constants: B=2, V=10000, N=16, CIN=128, COUT=64
#define V_CNT 10000
#define NB 16
#define TQ 16          // queries per block -> grid 1250 (round-5 lesson: 313 blocks
                       // = 1.2 blocks/CU = no latency hiding, 196us at VALUBusy 12%)
#define BQ_TOTAL 20000 // B*V

// ws float layout:
//   [0, 2880)      W45T[kj][d]     (45 x 64, transposed)
//   [2880, 3840)   WdP[r][k*5+c]   (20 x 48, permuted dir-weights)
//   [3840, 3900)   FN[f*3+axis]    (20 x 3 face normals)
#define WS_W45T  0
#define WS_WDP   2880
#define WS_FN    3840

__device__ __constant__ int FTC_d[20][5] = {
  {1,4,0,2,3},{2,0,1,4,3},{3,1,0,4,2},{4,2,0,3,1},{0,3,1,2,4},
  {3,2,0,4,1},{4,3,0,2,1},{0,4,1,2,3},{1,0,2,4,3},{2,1,0,4,3},
  {4,0,1,3,2},{0,1,2,3,4},{1,2,0,3,4},{2,3,0,1,4},{3,4,0,1,2},
  {1,3,0,2,4},{0,2,1,3,4},{4,1,0,3,2},{3,0,1,4,2},{2,4,0,1,3}};

constexpr int COLF[20] = {1,2,3,4,0,3,4,0,1,2,4,0,1,2,3,1,0,4,3,2};

constexpr int W9MAP[9][5] = {
  {0,1,2,2,2},{3,4,5,5,5},
  {9,10,11,12,13},{9,10,12,13,11},{9,10,13,11,12},
  {14,15,16,17,18},{14,15,17,18,16},{14,15,18,16,17},
  {6,7,8,8,8}};

__device__ __constant__ int FACES_d[20][3] = {
  {1,2,7},{1,3,7},{1,3,5},{1,4,5},{1,2,4},{2,7,8},{3,7,9},{3,5,11},{4,5,6},{2,4,10},
  {2,8,10},{7,8,9},{3,9,11},{5,6,11},{4,6,10},{0,8,10},{0,6,10},{0,6,11},{0,9,11},{0,8,9}};

#define PHI_F 1.61803398874989484820f
__device__ __constant__ float VS_d[12][3] = {
  {-1.f,PHI_F,0.f},{1.f,PHI_F,0.f},{-1.f,-PHI_F,0.f},{1.f,-PHI_F,0.f},
  {0.f,-1.f,PHI_F},{0.f,1.f,PHI_F},{0.f,-1.f,-PHI_F},{0.f,1.f,-PHI_F},
  {PHI_F,0.f,-1.f},{PHI_F,0.f,1.f},{-PHI_F,0.f,-1.f},{-PHI_F,0.f,1.f}};

__device__ __forceinline__ float fast_tanh(float x){
  float e = __expf(2.0f * x);
  return 1.0f - 2.0f * __builtin_amdgcn_rcpf(e + 1.0f);
}

#define FOR9(M)  M(0) M(1) M(2) M(3) M(4) M(5) M(6) M(7) M(8)
#define FOR4(M)  M(0) M(1) M(2) M(3)

// LDS geometry
#define DE5_QS 20              // de5s[c][q*20 + n]; q-stride 20 -> 16B-aligned n-quads
#define DE5_CS (16*DE5_QS)     // 320
#define PS_QS  231             // Ps[q][s*46 + kj]; 231%32=7 -> conflict-free per-q
#define PS_SS  46

// ---------------------------------------------------------------------------
// Kernel 1: weight prep (same as round 5).
// ---------------------------------------------------------------------------
__global__ __launch_bounds__(128) void prep_kernel(const float* __restrict__ W,
                                                   const float* __restrict__ Wdir,
                                                   float* __restrict__ ws){
  __shared__ float buf[128][20];
  __shared__ float part[19][4];
  __shared__ float w19s[19];
  int d = blockIdx.x;   // 0..64
  int c = threadIdx.x;  // 0..127

  const float* src = (d < 64) ? (W + ((size_t)d*128 + c)*19) : (Wdir + (size_t)c*19);
  #pragma unroll
  for (int tt = 0; tt < 19; ++tt) buf[c][tt] = src[tt];

  if (d == 64 && c < 20){
    float x=0.f, y=0.f, z=0.f;
    #pragma unroll
    for (int vv=0; vv<3; ++vv){
      int vi = FACES_d[c][vv];
      x += VS_d[vi][0]; y += VS_d[vi][1]; z += VS_d[vi][2];
    }
    float inv = rsqrtf(x*x + y*y + z*z);
    ws[WS_FN + c*3 + 0] = x*inv;
    ws[WS_FN + c*3 + 1] = y*inv;
    ws[WS_FN + c*3 + 2] = z*inv;
  }
  __syncthreads();

  if (c < 76){
    int j = c >> 2, g = c & 3;
    float s = 0.f;
    for (int i = g*32; i < g*32+32; ++i) s += buf[i][j];
    part[j][g] = s;
  }
  __syncthreads();
  if (c < 19) w19s[c] = (part[c][0]+part[c][1]) + (part[c][2]+part[c][3]);
  __syncthreads();

  if (d < 64){
    if (c < 45){
      int k = c / 5, j = c % 5;
      ws[WS_W45T + c*64 + d] = w19s[W9MAP[k][j]];   // transposed [kj][d]
    }
  } else {
    for (int i = c; i < 20*45; i += 128){
      int r  = i / 45;
      int kc = i - r*45;
      int k  = kc / 5, cc = kc - k*5;
      int jinv = 0;
      #pragma unroll
      for (int j = 0; j < 5; ++j) if (FTC_d[r][j] == cc) jinv = j;
      ws[WS_WDP + r*48 + kc] = w19s[W9MAP[k][jinv]];
    }
  }
}

// ---------------------------------------------------------------------------
// Fused kernel: grid 1250, block 256 = 4 waves. TQ=16 queries/block.
//  Phase A (thread = (q=t>>4, n=t&15)): de5 -> LDS SoA [c][q*20+n].
//  Phase B (lane = (q=l&15, nq=l>>4)): preload this lane's 4 n-quads of de5
//    into 20 VGPRs (5x ds_read_b128), then wave w runs r in {5w..5w+4}:
//    weights WdP[r] wave-uniform -> SGPRs (readfirstlane); 45 named-scalar
//    accumulators; direct LDS atomicAdd merge (4 nq-groups share addr; the
//    5 r's of one wave hit 5 distinct colors).
//  Phase C (thread = (q=t&15, dg=t>>4)): 4d x 5s output tile;
//    W45T staged in LDS, ds_read_b128 per kj.
// ---------------------------------------------------------------------------
__global__ __launch_bounds__(256, 4) void fold_kernel(const int*   __restrict__ nbr,
                                                      const float* __restrict__ verts,
                                                      const float* __restrict__ ws,
                                                      float* __restrict__ out){
  __shared__ float de5s[5*DE5_CS];     // 6400 B
  __shared__ float Ps[16*PS_QS];       // 14784 B
  __shared__ float Wl[45*64];          // 11520 B  -> total ~32.7 KB, 5 blocks/CU
  const int t = threadIdx.x;
  const int blockq0 = blockIdx.x * TQ;   // grid exactly 1250 -> all queries valid

  // stage W45T for phase C (coalesced; consumed after 2nd barrier)
  for (int i = t; i < 45*64; i += 256) Wl[i] = ws[WS_W45T + i];
  // zero Ps
  for (int i = t; i < 16*PS_QS; i += 256) Ps[i] = 0.f;

  // ---- Phase A: thread = (q, n) ----
  {
    const int q = t >> 4;
    const int n = t & 15;
    const int qg = blockq0 + q;
    const int qq = (qg >= V_CNT) ? qg - V_CNT : qg;
    const int b0 = qg - qq;
    const int idx = nbr[qg*NB + n];                // lanes consecutive n -> coalesced
    const float vx = verts[qg*3+0], vy = verts[qg*3+1], vz = verts[qg*3+2];
    const float* nv = verts + (size_t)(b0 + idx)*3;
    float dx = nv[0]-vx, dy = nv[1]-vy, dz = nv[2]-vz;
    float dd = dx*dx + dy*dy + dz*dz;
    float inv = (dd > 0.f) ? rsqrtf(dd) : 0.f;
    dx *= inv; dy *= inv; dz *= inv;
    const float* fnp = ws + WS_FN;                 // uniform -> s_loads
    float s0=0.f, s1=0.f, s2=0.f, s3=0.f, s4=0.f;
    #pragma unroll
    for (int f = 0; f < 20; ++f){
      float x = fnp[f*3+0]*dx + fnp[f*3+1]*dy + fnp[f*3+2]*dz;
      float th = fast_tanh(x);
      if      (COLF[f]==0) s0 += th;
      else if (COLF[f]==1) s1 += th;
      else if (COLF[f]==2) s2 += th;
      else if (COLF[f]==3) s3 += th;
      else                 s4 += th;
    }
    de5s[0*DE5_CS + q*DE5_QS + n] = s0;
    de5s[1*DE5_CS + q*DE5_QS + n] = s1;
    de5s[2*DE5_CS + q*DE5_QS + n] = s2;
    de5s[3*DE5_CS + q*DE5_QS + n] = s3;
    de5s[4*DE5_CS + q*DE5_QS + n] = s4;
  }
  __syncthreads();

  // ---- Phase B: lane = (q, nq); wave w owns r in {5w..5w+4} ----
  {
    const int lane = t & 63;
    const int w = __builtin_amdgcn_readfirstlane(t >> 6);
    const int q  = lane & 15;
    const int nq = lane >> 4;

    // preload 4 n's x 5 colors into 20 VGPRs (ds_read_b128 per color)
    const float* dbase = &de5s[q*DE5_QS + nq*4];   // 16B-aligned
#define DECL_E(C) const float4 ev##C = *(const float4*)(dbase + C*DE5_CS);
    DECL_E(0) DECL_E(1) DECL_E(2) DECL_E(3) DECL_E(4)
#undef DECL_E

    #pragma unroll 1
    for (int rr = 0; rr < 5; ++rr){
      const int r = w*5 + rr;                      // wave-uniform
      const int sr = FTC_d[r][0];
      int ji0=0, ji1=0, ji2=0, ji3=0, ji4=0;
      #pragma unroll
      for (int j = 0; j < 5; ++j){
        int f = FTC_d[r][j];
        if (f==0) ji0=j; else if (f==1) ji1=j; else if (f==2) ji2=j;
        else if (f==3) ji3=j; else ji4=j;
      }

      const float* wp = ws + WS_WDP + r*48;        // wave-uniform -> SGPRs
#define DECL_P(K) const float p##K##0=wp[K*5+0], p##K##1=wp[K*5+1], \
      p##K##2=wp[K*5+2], p##K##3=wp[K*5+3], p##K##4=wp[K*5+4];
      FOR9(DECL_P)
#undef DECL_P
#define DECL_A(K) float aC##K##0=0.f, aC##K##1=0.f, aC##K##2=0.f, \
      aC##K##3=0.f, aC##K##4=0.f;
      FOR9(DECL_A)
#undef DECL_A

#define KSTEP(K) { \
      float a = fmaxf(p##K##0*E0 + p##K##1*E1 + p##K##2*E2 \
                    + p##K##3*E3 + p##K##4*E4, 0.f); \
      aC##K##0 = fmaf(a, E0, aC##K##0); \
      aC##K##1 = fmaf(a, E1, aC##K##1); \
      aC##K##2 = fmaf(a, E2, aC##K##2); \
      aC##K##3 = fmaf(a, E3, aC##K##3); \
      aC##K##4 = fmaf(a, E4, aC##K##4); }
#define NSTEP(NI) { \
      const float E0 = ev0.NI, E1 = ev1.NI, E2 = ev2.NI, \
                  E3 = ev3.NI, E4 = ev4.NI; \
      FOR9(KSTEP) }
      NSTEP(x) NSTEP(y) NSTEP(z) NSTEP(w)
#undef NSTEP
#undef KSTEP

      // all 64 lanes atomic; 4 nq-groups share addr (4-way ds_add, no-return)
      float* base = &Ps[q*PS_QS + sr*PS_SS];
      float* bj0 = base + ji0; float* bj1 = base + ji1; float* bj2 = base + ji2;
      float* bj3 = base + ji3; float* bj4 = base + ji4;
#define KAT(K) atomicAdd(bj0 + K*5, aC##K##0); \
               atomicAdd(bj1 + K*5, aC##K##1); \
               atomicAdd(bj2 + K*5, aC##K##2); \
               atomicAdd(bj3 + K*5, aC##K##3); \
               atomicAdd(bj4 + K*5, aC##K##4);
      FOR9(KAT)
#undef KAT
    }
  }
  __syncthreads();

  // ---- Phase C: thread = (q, dg); 4 d x 5 s tile ----
  {
    const int q  = t & 15;
    const int dg = t >> 4;                         // 0..15 -> d = dg*4 + dd
    const float* pq = &Ps[q*PS_QS];
#define DECL_O(D) float o##D##0=0.f,o##D##1=0.f,o##D##2=0.f,o##D##3=0.f,o##D##4=0.f;
    FOR4(DECL_O)
#undef DECL_O
    for (int kj = 0; kj < 45; ++kj){
      float4 wv = *(const float4*)&Wl[kj*64 + dg*4];  // ds_read_b128, aligned
      float b0 = pq[0*PS_SS + kj];
      float b1 = pq[1*PS_SS + kj];
      float b2 = pq[2*PS_SS + kj];
      float b3 = pq[3*PS_SS + kj];
      float b4 = pq[4*PS_SS + kj];
#define GST(D, FLD) { float wf = wv.FLD; \
      o##D##0 = fmaf(wf, b0, o##D##0); \
      o##D##1 = fmaf(wf, b1, o##D##1); \
      o##D##2 = fmaf(wf, b2, o##D##2); \
      o##D##3 = fmaf(wf, b3, o##D##3); \
      o##D##4 = fmaf(wf, b4, o##D##4); }
      GST(0,x) GST(1,y) GST(2,z) GST(3,w)
#undef GST
    }
    const int qg = blockq0 + q;
    const int b  = (qg >= V_CNT) ? 1 : 0;
    const int qq = qg - b*V_CNT;
    float* ob = out + (size_t)b*3200000 + (size_t)(dg*4)*50000 + (size_t)qq*5;
#define OST(D) { float* o_ = ob + (size_t)(D)*50000; \
    o_[0]=o##D##0; o_[1]=o##D##1; o_[2]=o##D##2; o_[3]=o##D##3; o_[4]=o##D##4; }
    FOR4(OST)
#undef OST
  }
}

extern "C" void kernel_launch(void* const* d_in, const int* in_sizes, int n_in,
                              void* d_out, int out_size, void* d_ws, size_t ws_size,
                              hipStream_t stream){
  const int*   nbr   = (const int*)d_in[0];
  const float* verts = (const float*)d_in[1];
  const float* W     = (const float*)d_in[2];
  const float* Wdir  = (const float*)d_in[3];
  float* out = (float*)d_out;
  float* ws  = (float*)d_ws;

  hipLaunchKernelGGL(prep_kernel, dim3(65), dim3(128), 0, stream, W, Wdir, ws);
  hipLaunchKernelGGL(fold_kernel, dim3(BQ_TOTAL/TQ), dim3(256), 0, stream,
                     nbr, verts, ws, out);
}